// Round 9
// baseline (218.632 us; speedup 1.0000x reference)
//
#include <hip/hip_runtime.h>
#include <hip/hip_bf16.h>
#include <math.h>

#define BB 4
#define SS 1024
#define DD 1024
#define NH 16
#define DKH 64

typedef __attribute__((ext_vector_type(8))) short bf16x8;    // MFMA A/B frag (4 VGPRs)
typedef __attribute__((ext_vector_type(4))) float f32x4;     // 16x16 C/D frag
typedef __attribute__((ext_vector_type(16))) float f32x16;   // 32x32 C/D frag

__device__ __forceinline__ ushort f2bf(float f) {
  __hip_bfloat16 h = __float2bfloat16(f);
  return *(ushort*)&h;
}

__device__ __forceinline__ bf16x8 pack8(float4 a, float4 b) {
  bf16x8 r;
  r[0] = (short)f2bf(a.x); r[1] = (short)f2bf(a.y);
  r[2] = (short)f2bf(a.z); r[3] = (short)f2bf(a.w);
  r[4] = (short)f2bf(b.x); r[5] = (short)f2bf(b.y);
  r[6] = (short)f2bf(b.z); r[7] = (short)f2bf(b.w);
  return r;
}

// async global -> LDS, 16 B per lane; LDS dest = wave-uniform base + lane*16
__device__ __forceinline__ void async16(const void* g, void* l) {
  __builtin_amdgcn_global_load_lds(
      (const __attribute__((address_space(1))) unsigned int*)g,
      (__attribute__((address_space(3))) unsigned int*)l, 16, 0, 0);
}

// ---------------------------------------------------------------------------
// prep_all (reductions first, conversions grid-stride x8):
//  [0,64)        wo_sum: block streams 16 contiguous Wo rows, 4 atomicAdds
//                (column base rotated by bid*4 to de-phase cross-block atomics)
//  64            bo_mean (fp32, exact, deterministic)
//  [65,577)      maskOK = all-ones test per 128x64 mask tile
//  [577,1345)    q,k,v fp32 -> dense bf16 (768 blocks x 8 chunks)
//  [1345,1537)   Wq/Wk/Wv fp32 -> dense bf16 (192 blocks x 8 chunks)
// ---------------------------------------------------------------------------
__global__ __launch_bounds__(256) void prep_all(
    const float* __restrict__ Xq, const float* __restrict__ Xk, const float* __restrict__ Xv,
    const int* __restrict__ mask,
    const float* __restrict__ Wq, const float* __restrict__ Wk, const float* __restrict__ Wv,
    const float* __restrict__ Wo, const float* __restrict__ bo,
    ushort* __restrict__ Wb, ushort* __restrict__ Ab,
    float* __restrict__ wo_sum, float* __restrict__ bo_mean,
    int* __restrict__ maskOK) {
  __shared__ int smi[4];
  const int bid = blockIdx.x;
  const int tid = threadIdx.x;

  if (bid < 64) {
    const int row0 = bid * 16;
    const int c = (tid + bid * 4) & 255;
    float4 acc = make_float4(0.f, 0.f, 0.f, 0.f);
#pragma unroll
    for (int r = 0; r < 16; ++r) {
      const float4 v = *(const float4*)(Wo + (size_t)(row0 + r) * DD + c * 4);
      acc.x += v.x; acc.y += v.y; acc.z += v.z; acc.w += v.w;
    }
    atomicAdd(&wo_sum[c * 4 + 0], acc.x);
    atomicAdd(&wo_sum[c * 4 + 1], acc.y);
    atomicAdd(&wo_sum[c * 4 + 2], acc.z);
    atomicAdd(&wo_sum[c * 4 + 3], acc.w);
    return;
  }

  if (bid == 64) {
    if (tid < 64) {
      float s = 0.f;
      for (int i = tid; i < 1024; i += 64) s += bo[i];
#pragma unroll
      for (int off = 1; off < 64; off <<= 1) s += __shfl_xor(s, off);
      if (tid == 0) *bo_mean = s * (1.0f / 1024.0f);
    }
    return;
  }

  if (bid < 577) {
    const int m = bid - 65;            // 0..511
    const int kt = m & 15, qt = (m >> 4) & 7, b = m >> 7;
    const int row = tid >> 1, half = tid & 1;
    const int* p = mask + ((size_t)b * SS + qt * 128 + row) * SS + kt * 64 + half * 32;
    int ok = 1;
#pragma unroll
    for (int j = 0; j < 8; ++j) {
      const int4 mm = *(const int4*)(p + j * 4);
      ok &= (mm.x != 0) & (mm.y != 0) & (mm.z != 0) & (mm.w != 0);
    }
    const unsigned long long bal = __ballot(ok);
    if ((tid & 63) == 0) smi[tid >> 6] = (bal == ~0ULL) ? 1 : 0;
    __syncthreads();
    if (tid == 0) maskOK[(b * 8 + qt) * 16 + kt] = smi[0] & smi[1] & smi[2] & smi[3];
    return;
  }

  if (bid < 1345) {
    const int c0 = bid - 577;          // 0..767
#pragma unroll
    for (int it = 0; it < 8; ++it) {
      const size_t g = (size_t)(c0 + it * 768) * 2048 + (size_t)tid * 8;
      const int t = (int)(g >> 22);
      const float* base = (t == 0) ? Xq : (t == 1) ? Xk : Xv;
      const size_t off = g & 4194303;
      const float4 f0 = *(const float4*)(base + off);
      const float4 f1 = *(const float4*)(base + off + 4);
      *(bf16x8*)(Ab + g) = pack8(f0, f1);
    }
    return;
  }

  {
    const int c0 = bid - 1345;         // 0..191
#pragma unroll
    for (int it = 0; it < 8; ++it) {
      const size_t g = (size_t)(c0 + it * 192) * 2048 + (size_t)tid * 8;
      const int t = (int)(g >> 20);
      const float* W = (t == 0) ? Wq : (t == 1) ? Wk : Wv;
      const size_t off = g & 1048575;
      const float4 f0 = *(const float4*)(W + off);
      const float4 f1 = *(const float4*)(W + off + 4);
      *(bf16x8*)(Wb + g) = pack8(f0, f1);
    }
  }
}

// ---------------------------------------------------------------------------
// bf16 MFMA GEMM, T4 counted-vmcnt round. Round-8 (BK=32, 2-buf, one
// __syncthreads/iter) measured 43 us / MfmaUtil 23% / occ 25%. The remaining
// diagnosed waste: __syncthreads' implicit vmcnt(0) drains the stage issued
// THIS iter (needed only next iter) -> exposed L2 latency tail every iter
// (T4/m218: counted vmcnt IS the pipeline gain). Now:
//  - triple buffer As[3]/Ws[3] (48 KB -> still 3 blocks/CU, 144<=160 KB);
//  - iter i stages tile i+2 into buf[(i+2)%3] (WAR-safe: that buffer was
//    read in iter i-1, closed by its barrier — same distance as round 8);
//  - end-of-iter: s_waitcnt vmcnt(4) (current iter's 4 loads may stay in
//    flight; tile i+1, staged a full iteration ago, is guaranteed landed)
//    + sched_barrier(0) + raw s_barrier. Tail iters drain to 0.
//  - raw-barrier safety: all ds_reads are consumed by MFMAs before the
//    barrier in program order (compiler lgkm-waits; sched_barrier pins).
// LDS layout/swizzle and head-major C store unchanged from round 8.
// ---------------------------------------------------------------------------
__global__ __launch_bounds__(256) void gemm_qkv_bf16(
    const ushort* __restrict__ Ab, const ushort* __restrict__ Wb,
    const float* __restrict__ bq, const float* __restrict__ bk, const float* __restrict__ bv,
    ushort* __restrict__ QKVb) {
  const int z = blockIdx.z;
  const char* A = (const char*)(Ab + (size_t)z * 4194304);
  const char* W = (const char*)(Wb + (size_t)z * 1048576);
  const float* bias = (z == 0) ? bq : (z == 1) ? bk : bv;
  ushort* Cz = QKVb + (size_t)z * 4194304;
  const float scale = (z == 0) ? 0.125f : 1.0f;

  __shared__ ushort As[3][4096];  // 128 rows x 32 elts, slot-swizzled, 8 KB/buf
  __shared__ ushort Ws[3][4096];

  const int tid = threadIdx.x;
  const int lane = tid & 63, w = tid >> 6;
  const int l31 = lane & 31, kh = lane >> 5;   // 32x32 frag coords
  const int wn = w & 1, wm = w >> 1;
  const int m0 = blockIdx.x * 128, n0 = blockIdx.y * 128;

  // staging geometry: 512 chunks of 16 B; thread t covers L=t and L=256+t.
  // L -> row = L>>2, slot = L&3. Stored slot s holds global chunk
  // c = (s - ((row>>1)&3)) & 3 (inverse of the reader swizzle).
  const int rowA = tid >> 2;                       // rows 0..63
  const int cA = ((tid & 3) - ((rowA >> 1) & 3)) & 3;
  const int rowB = 64 + (tid >> 2);                // rows 64..127
  const int cB = ((tid & 3) - ((rowB >> 1) & 3)) & 3;

#define STAGE_TILE(T, B)                                                               \
  do {                                                                                 \
    const int k0s = (T) * 32;                                                          \
    async16(A + ((size_t)(m0 + rowA) * DD + k0s + cA * 8) * 2, &As[B][tid * 8]);       \
    async16(W + ((size_t)(n0 + rowA) * DD + k0s + cA * 8) * 2, &Ws[B][tid * 8]);       \
    async16(A + ((size_t)(m0 + rowB) * DD + k0s + cB * 8) * 2, &As[B][2048 + tid * 8]);\
    async16(W + ((size_t)(n0 + rowB) * DD + k0s + cB * 8) * 2, &Ws[B][2048 + tid * 8]);\
  } while (0)

  f32x16 acc[2][2];
#pragma unroll
  for (int mt = 0; mt < 2; ++mt)
#pragma unroll
    for (int nt = 0; nt < 2; ++nt)
#pragma unroll
      for (int r = 0; r < 16; ++r) acc[mt][nt][r] = 0.f;

  // prologue: stage tiles 0 and 1; wait for tile 0 only (tile 1 in flight)
  STAGE_TILE(0, 0);
  STAGE_TILE(1, 1);
  asm volatile("s_waitcnt vmcnt(4)" ::: "memory");
  __builtin_amdgcn_sched_barrier(0);
  __builtin_amdgcn_s_barrier();  // tile 0 visible

  for (int i = 0; i < 32; ++i) {
    const int cur = i - (i / 3) * 3;  // i % 3
    // stage tile i+2 (into the buffer read in iter i-1) -> 2-deep pipeline
    if (i < 30) {
      const int bn = (i + 2) - ((i + 2) / 3) * 3;
      STAGE_TILE(i + 2, bn);
    }
    // compute from the live buffer (2 K=16 steps)
#pragma unroll
    for (int ks = 0; ks < 2; ++ks) {
      bf16x8 wf[2], af[2];
#pragma unroll
      for (int nt = 0; nt < 2; ++nt) {
        const int r = wn * 64 + nt * 32 + l31;
        const int s = (ks * 2 + kh + ((r >> 1) & 3)) & 3;
        wf[nt] = *(const bf16x8*)&Ws[cur][r * 32 + s * 8];
      }
#pragma unroll
      for (int mt = 0; mt < 2; ++mt) {
        const int r = wm * 64 + mt * 32 + l31;
        const int s = (ks * 2 + kh + ((r >> 1) & 3)) & 3;
        af[mt] = *(const bf16x8*)&As[cur][r * 32 + s * 8];
      }
#pragma unroll
      for (int mt = 0; mt < 2; ++mt)
#pragma unroll
        for (int nt = 0; nt < 2; ++nt)
          acc[mt][nt] = __builtin_amdgcn_mfma_f32_32x32x16_bf16(wf[nt], af[mt], acc[mt][nt], 0, 0, 0);
    }
    // counted drain: tile i+1 (staged last iter) guaranteed landed; the 4
    // loads issued THIS iter may remain in flight across the barrier.
    if (i < 30) {
      asm volatile("s_waitcnt vmcnt(4)" ::: "memory");
    } else {
      asm volatile("s_waitcnt vmcnt(0)" ::: "memory");
    }
    __builtin_amdgcn_sched_barrier(0);
    __builtin_amdgcn_s_barrier();
  }
#undef STAGE_TILE

  // epilogue: bias + scale; head-major store [head][row][64]
  const int hh = blockIdx.y * 2 + wn;     // head owning this 64-col slab
#pragma unroll
  for (int nt = 0; nt < 2; ++nt) {
#pragma unroll
    for (int g = 0; g < 4; ++g) {
      const int ng = n0 + wn * 64 + nt * 32 + kh * 4 + g * 8;
      const int d = nt * 32 + kh * 4 + g * 8;          // dim within head
      const float4 b4 = *(const float4*)(bias + ng);
#pragma unroll
      for (int mt = 0; mt < 2; ++mt) {
        const int row = m0 + wm * 64 + mt * 32 + l31;
        ushort4 pk;
        pk.x = f2bf((acc[mt][nt][g * 4 + 0] + b4.x) * scale);
        pk.y = f2bf((acc[mt][nt][g * 4 + 1] + b4.y) * scale);
        pk.z = f2bf((acc[mt][nt][g * 4 + 2] + b4.z) * scale);
        pk.w = f2bf((acc[mt][nt][g * 4 + 3] + b4.w) * scale);
        *(ushort4*)&Cz[(size_t)hh * 262144 + (size_t)row * 64 + d] = pk;
      }
    }
  }
}

// ---------------------------------------------------------------------------
// MFMA flash attention — round-6 kernel, unchanged (dropped below the 41 us
// workspace-fill dispatch). Head-major QKV; K staged once per block via
// async16 into a double-buffered, granule-XOR-swizzled LDS tile; V-reg
// prefetch; two-barrier V publication; setprio MFMA clusters; okbits hoist.
// Grid (16,8,4), 2 blocks/CU.
// ---------------------------------------------------------------------------
__global__ __launch_bounds__(256) void flash_mfma(
    const ushort* __restrict__ QKVb, const int* __restrict__ mask,
    const int* __restrict__ maskOK, float* __restrict__ X) {
  __shared__ ushort Ks[2][4096];   // K tile 64 keys x 64 d, granule-swizzled
  __shared__ ushort Vt[64 * 72];   // V^T [d][key], padded
  __shared__ ushort Ps[128 * 72];  // P^T [q_local][key], padded

  const int tid = threadIdx.x;
  const int lane = tid & 63, w = tid >> 6;
  const int quad = lane >> 4, l15 = lane & 15;
  const int h = blockIdx.x, qblk = blockIdx.y, b = blockIdx.z;
  const int qbase = qblk * 128 + w * 32;

  // head-major bases: [h][4096][64]
  const ushort* Qh = QKVb + (size_t)h * 262144;
  const ushort* Kh = QKVb + 4194304 + (size_t)h * 262144 + (size_t)(b * SS) * 64;
  const ushort* Vh = QKVb + 8388608 + (size_t)h * 262144 + (size_t)(b * SS) * 64;

  bf16x8 qf[2][2];
#pragma unroll
  for (int qt = 0; qt < 2; ++qt)
#pragma unroll
    for (int ks = 0; ks < 2; ++ks)
      qf[qt][ks] = *(const bf16x8*)(Qh + (size_t)(b * SS + qbase + qt * 16 + l15) * 64 +
                                    ks * 32 + quad * 8);

  // per-tile mask flags -> bitmask
  unsigned okbits = 0;
  {
    const int* mkp = maskOK + (b * 8 + qblk) * 16;
#pragma unroll
    for (int i = 0; i < 16; ++i) okbits |= (mkp[i] ? 1u : 0u) << i;
  }

  f32x4 o[4][2];
  const f32x4 z4 = {0.f, 0.f, 0.f, 0.f};
#pragma unroll
  for (int dt = 0; dt < 4; ++dt)
#pragma unroll
    for (int qt = 0; qt < 2; ++qt) o[dt][qt] = z4;
  float l_run[2] = {0.f, 0.f};

  const int vp = tid & 31;   // key pair index
  const int vdc = tid >> 5;  // d-chunk (8 dims)
  const ushort* Vg = Vh + vdc * 8;
  uint* VtU = (uint*)Vt;
  const int* Mb = mask + (size_t)b * SS * SS;

  // K staging geometry: thread covers LDS chunks {tid, 256+tid} (16B each).
  const int r8k = tid >> 3;              // row within 32-row half
  const int gk = (tid & 7) ^ (r8k & 7);  // pre-swizzled source granule
  const int xk = l15 & 7;                // reader swizzle key (row&7)

  union U8 { uint4 u; ushort s[8]; };

  // ---- prologue: async K(0) -> Ks[0]; V(0) pair into regs ----
  async16(Kh + (size_t)r8k * 64 + gk * 8, &Ks[0][(size_t)tid * 8]);
  async16(Kh + (size_t)(32 + r8k) * 64 + gk * 8, &Ks[0][2048 + (size_t)tid * 8]);
  U8 v0c, v1c;
  v0c.u = *(const uint4*)(Vg + (size_t)(2 * vp) * 64);
  v1c.u = *(const uint4*)(Vg + (size_t)(2 * vp + 1) * 64);

  for (int kt = 0; kt < 16; ++kt) {
    const int k064 = kt * 64;
    const int cur = kt & 1;

    __builtin_amdgcn_s_barrier();   // B1: all waves done reading prior Vt/Ks
    // V transpose-write from prefetched regs; the implicit vmcnt wait for
    // v0c/v1c also drains this thread's older K asyncs (FIFO) -> Ks[cur]
    // complete in every thread before B2.
#pragma unroll
    for (int j = 0; j < 8; ++j)
      VtU[(vdc * 8 + j) * 36 + vp] = (uint)v0c.s[j] | ((uint)v1c.s[j] << 16);
    // stage K(kt+1) into the spare buffer (drains before B2 of iter kt+1)
    if (kt < 15) {
      const ushort* Kt = Kh + (size_t)(k064 + 64) * 64;
      async16(Kt + (size_t)r8k * 64 + gk * 8, &Ks[cur ^ 1][(size_t)tid * 8]);
      async16(Kt + (size_t)(32 + r8k) * 64 + gk * 8, &Ks[cur ^ 1][2048 + (size_t)tid * 8]);
    }
    asm volatile("s_waitcnt lgkmcnt(0)" ::: "memory");
    __builtin_amdgcn_sched_barrier(0);
    __builtin_amdgcn_s_barrier();   // B2: Vt + Ks[cur] visible to all waves

    // ---- V prefetch for tile kt+1 (consumed next iteration) ----
    const int kn = (kt < 15) ? (k064 + 64) : 0;  // clamp: dummy reload
    U8 v0n, v1n;
    v0n.u = *(const uint4*)(Vg + (size_t)(kn + 2 * vp) * 64);
    v1n.u = *(const uint4*)(Vg + (size_t)(kn + 2 * vp + 1) * 64);

    // ---- QK^T: K frags from swizzled LDS tile ----
    f32x4 s[4][2];
    __builtin_amdgcn_s_setprio(1);
#pragma unroll
    for (int mt = 0; mt < 4; ++mt) {
      const int rr = mt * 16 + l15;
      bf16x8 kf0 = *(const bf16x8*)&Ks[cur][rr * 64 + ((quad) ^ xk) * 8];
      bf16x8 kf1 = *(const bf16x8*)&Ks[cur][rr * 64 + ((4 + quad) ^ xk) * 8];
#pragma unroll
      for (int qt = 0; qt < 2; ++qt) {
        f32x4 a = z4;
        a = __builtin_amdgcn_mfma_f32_16x16x32_bf16(kf0, qf[qt][0], a, 0, 0, 0);
        a = __builtin_amdgcn_mfma_f32_16x16x32_bf16(kf1, qf[qt][1], a, 0, 0, 0);
        s[mt][qt] = a;
      }
    }
    __builtin_amdgcn_s_setprio(0);

    if (!((okbits >> kt) & 1)) {
#pragma unroll
      for (int mt = 0; mt < 4; ++mt)
#pragma unroll
        for (int qt = 0; qt < 2; ++qt)
#pragma unroll
          for (int reg = 0; reg < 4; ++reg) {
            const int q = qbase + qt * 16 + l15;
            const int key = k064 + mt * 16 + quad * 4 + reg;
            if (Mb[(size_t)q * SS + key] == 0) s[mt][qt][reg] = -1e9f;
          }
    }

#pragma unroll
    for (int qt = 0; qt < 2; ++qt) {
      float rs = 0.f;
#pragma unroll
      for (int mt = 0; mt < 4; ++mt) {
#pragma unroll
        for (int reg = 0; reg < 4; ++reg) {
          const float p = __expf(s[mt][qt][reg]);
          s[mt][qt][reg] = p;
          rs += p;
        }
      }
      l_run[qt] += rs;
#pragma unroll
      for (int mt = 0; mt < 4; ++mt) {
        ushort4 pk;
        pk.x = f2bf(s[mt][qt][0]);
        pk.y = f2bf(s[mt][qt][1]);
        pk.z = f2bf(s[mt][qt][2]);
        pk.w = f2bf(s[mt][qt][3]);
        *(ushort4*)&Ps[(w * 32 + qt * 16 + l15) * 72 + mt * 16 + quad * 4] = pk;
      }
    }

    // ---- PV (Ps same-wave; Vt barrier-protected) ----
    bf16x8 pf[2][2];
#pragma unroll
    for (int qt = 0; qt < 2; ++qt)
#pragma unroll
      for (int ks = 0; ks < 2; ++ks)
        pf[qt][ks] = *(const bf16x8*)&Ps[(w * 32 + qt * 16 + l15) * 72 + ks * 32 + quad * 8];
    __builtin_amdgcn_s_setprio(1);
#pragma unroll
    for (int dt = 0; dt < 4; ++dt) {
      bf16x8 vf0 = *(const bf16x8*)&Vt[(dt * 16 + l15) * 72 + quad * 8];
      bf16x8 vf1 = *(const bf16x8*)&Vt[(dt * 16 + l15) * 72 + 32 + quad * 8];
#pragma unroll
      for (int qt = 0; qt < 2; ++qt) {
        o[dt][qt] = __builtin_amdgcn_mfma_f32_16x16x32_bf16(vf0, pf[qt][0], o[dt][qt], 0, 0, 0);
        o[dt][qt] = __builtin_amdgcn_mfma_f32_16x16x32_bf16(vf1, pf[qt][1], o[dt][qt], 0, 0, 0);
      }
    }
    __builtin_amdgcn_s_setprio(0);

    // rotate prefetched V regs
    v0c.u = v0n.u;
    v1c.u = v1n.u;
  }

#pragma unroll
  for (int qt = 0; qt < 2; ++qt) {
    float l = l_run[qt];
    l += __shfl_xor(l, 16);
    l += __shfl_xor(l, 32);
    const float inv = 1.0f / l;
#pragma unroll
    for (int dt = 0; dt < 4; ++dt) {
      const f32x4 ov = o[dt][qt] * inv;
      *(f32x4*)(X + (size_t)(b * SS + qbase + qt * 16 + l15) * DD +
                h * DKH + dt * 16 + quad * 4) = ov;
    }
  }
}

// ---------------------------------------------------------------------------
// Epilogue: 4 rows per block (grid 1024), single barrier, wo slice in regs.
// xt = threshold(x,0.2); x1 = dot(xt,wo_sum)/1024 + bo_mean; out = xt + x1
// ---------------------------------------------------------------------------
__global__ __launch_bounds__(256) void epilogue_kernel(float* __restrict__ X,
                                                       const float* __restrict__ wo_sum,
                                                       const float* __restrict__ bo_mean) {
  __shared__ float red[4][4];
  const int tid = threadIdx.x;
  const float4 wv = *(const float4*)(wo_sum + tid * 4);
  const float bm = *bo_mean;
  float4 xt[4];
#pragma unroll
  for (int r = 0; r < 4; ++r) {
    const int row = blockIdx.x * 4 + r;
    const float4 x = *(const float4*)(X + (size_t)row * DD + tid * 4);
    xt[r].x = (x.x > 0.2f) ? x.x : 0.f;
    xt[r].y = (x.y > 0.2f) ? x.y : 0.f;
    xt[r].z = (x.z > 0.2f) ? x.z : 0.f;
    xt[r].w = (x.w > 0.2f) ? x.w : 0.f;
    float part = xt[r].x * wv.x + xt[r].y * wv.y + xt[r].z * wv.z + xt[r].w * wv.w;
#pragma unroll
    for (int off = 1; off < 64; off <<= 1) part += __shfl_xor(part, off);
    if ((tid & 63) == 0) red[r][tid >> 6] = part;
  }
  __syncthreads();
#pragma unroll
  for (int r = 0; r < 4; ++r) {
    const int row = blockIdx.x * 4 + r;
    const float x1 = ((red[r][0] + red[r][1]) + (red[r][2] + red[r][3])) * (1.0f / 1024.0f) + bm;
    const float4 o = make_float4(xt[r].x + x1, xt[r].y + x1, xt[r].z + x1, xt[r].w + x1);
    *(float4*)(X + (size_t)row * DD + tid * 4) = o;
  }
}

// ---------------------------------------------------------------------------
extern "C" void kernel_launch(void* const* d_in, const int* in_sizes, int n_in,
                              void* d_out, int out_size, void* d_ws, size_t ws_size,
                              hipStream_t stream) {
  const float* Xq = (const float*)d_in[0];
  const float* Xk = (const float*)d_in[1];
  const float* Xv = (const float*)d_in[2];
  const int* mask = (const int*)d_in[3];
  const float* Wq = (const float*)d_in[4];
  const float* bq = (const float*)d_in[5];
  const float* Wk = (const float*)d_in[6];
  const float* bk = (const float*)d_in[7];
  const float* Wv = (const float*)d_in[8];
  const float* bv = (const float*)d_in[9];
  const float* Wo = (const float*)d_in[10];
  const float* bo = (const float*)d_in[11];

  // workspace (~54 MB): Wb 6 MB + Ab 24 MB + QKVb 24 MB + tails
  ushort* Wb = (ushort*)d_ws;                     // 3 x 1048576 bf16
  ushort* Ab = Wb + (size_t)3 * 1048576;          // 3 x 4194304 bf16 (dense q,k,v)
  ushort* QKVb = Ab + (size_t)3 * 4194304;        // 3 x 4194304 bf16 (head-major)
  float* wo_sum = (float*)(QKVb + (size_t)3 * 4194304);
  float* bo_mean = wo_sum + 1024;
  int* maskOK = (int*)(bo_mean + 1);              // 512 ints
  float* X = (float*)d_out;

  hipMemsetAsync(wo_sum, 0, 1024 * sizeof(float), stream);

  prep_all<<<1537, 256, 0, stream>>>(Xq, Xk, Xv, mask, Wq, Wk, Wv, Wo, bo,
                                     Wb, Ab, wo_sum, bo_mean, maskOK);

  gemm_qkv_bf16<<<dim3(32, 8, 3), 256, 0, stream>>>(Ab, Wb, bq, bk, bv, QKVb);

  flash_mfma<<<dim3(16, 8, 4), 256, 0, stream>>>(QKVb, mask, maskOK, X);

  epilogue_kernel<<<1024, 256, 0, stream>>>(X, wo_sum, bo_mean);
}

// Round 10
// 214.166 us; speedup vs baseline: 1.0209x; 1.0209x over previous
//
#include <hip/hip_runtime.h>
#include <hip/hip_bf16.h>
#include <math.h>

#define BB 4
#define SS 1024
#define DD 1024
#define NH 16
#define DKH 64

typedef __attribute__((ext_vector_type(8))) short bf16x8;    // MFMA A/B frag (4 VGPRs)
typedef __attribute__((ext_vector_type(4))) float f32x4;     // 16x16 C/D frag
typedef __attribute__((ext_vector_type(16))) float f32x16;   // 32x32 C/D frag

__device__ __forceinline__ ushort f2bf(float f) {
  __hip_bfloat16 h = __float2bfloat16(f);
  return *(ushort*)&h;
}

__device__ __forceinline__ bf16x8 pack8(float4 a, float4 b) {
  bf16x8 r;
  r[0] = (short)f2bf(a.x); r[1] = (short)f2bf(a.y);
  r[2] = (short)f2bf(a.z); r[3] = (short)f2bf(a.w);
  r[4] = (short)f2bf(b.x); r[5] = (short)f2bf(b.y);
  r[6] = (short)f2bf(b.z); r[7] = (short)f2bf(b.w);
  return r;
}

// async global -> LDS, 16 B per lane; LDS dest = wave-uniform base + lane*16
__device__ __forceinline__ void async16(const void* g, void* l) {
  __builtin_amdgcn_global_load_lds(
      (const __attribute__((address_space(1))) unsigned int*)g,
      (__attribute__((address_space(3))) unsigned int*)l, 16, 0, 0);
}

// ---------------------------------------------------------------------------
// prep_all (reductions first, conversions grid-stride x8):
//  [0,64)        wo_sum: block streams 16 contiguous Wo rows, 4 atomicAdds
//                (column base rotated by bid*4 to de-phase cross-block atomics)
//  64            bo_mean (fp32, exact, deterministic)
//  [65,577)      maskOK = all-ones test per 128x64 mask tile
//  [577,1345)    q,k,v fp32 -> dense bf16 (768 blocks x 8 chunks)
//  [1345,1537)   Wq/Wk/Wv fp32 -> dense bf16 (192 blocks x 8 chunks)
// ---------------------------------------------------------------------------
__global__ __launch_bounds__(256) void prep_all(
    const float* __restrict__ Xq, const float* __restrict__ Xk, const float* __restrict__ Xv,
    const int* __restrict__ mask,
    const float* __restrict__ Wq, const float* __restrict__ Wk, const float* __restrict__ Wv,
    const float* __restrict__ Wo, const float* __restrict__ bo,
    ushort* __restrict__ Wb, ushort* __restrict__ Ab,
    float* __restrict__ wo_sum, float* __restrict__ bo_mean,
    int* __restrict__ maskOK) {
  __shared__ int smi[4];
  const int bid = blockIdx.x;
  const int tid = threadIdx.x;

  if (bid < 64) {
    const int row0 = bid * 16;
    const int c = (tid + bid * 4) & 255;
    float4 acc = make_float4(0.f, 0.f, 0.f, 0.f);
#pragma unroll
    for (int r = 0; r < 16; ++r) {
      const float4 v = *(const float4*)(Wo + (size_t)(row0 + r) * DD + c * 4);
      acc.x += v.x; acc.y += v.y; acc.z += v.z; acc.w += v.w;
    }
    atomicAdd(&wo_sum[c * 4 + 0], acc.x);
    atomicAdd(&wo_sum[c * 4 + 1], acc.y);
    atomicAdd(&wo_sum[c * 4 + 2], acc.z);
    atomicAdd(&wo_sum[c * 4 + 3], acc.w);
    return;
  }

  if (bid == 64) {
    if (tid < 64) {
      float s = 0.f;
      for (int i = tid; i < 1024; i += 64) s += bo[i];
#pragma unroll
      for (int off = 1; off < 64; off <<= 1) s += __shfl_xor(s, off);
      if (tid == 0) *bo_mean = s * (1.0f / 1024.0f);
    }
    return;
  }

  if (bid < 577) {
    const int m = bid - 65;            // 0..511
    const int kt = m & 15, qt = (m >> 4) & 7, b = m >> 7;
    const int row = tid >> 1, half = tid & 1;
    const int* p = mask + ((size_t)b * SS + qt * 128 + row) * SS + kt * 64 + half * 32;
    int ok = 1;
#pragma unroll
    for (int j = 0; j < 8; ++j) {
      const int4 mm = *(const int4*)(p + j * 4);
      ok &= (mm.x != 0) & (mm.y != 0) & (mm.z != 0) & (mm.w != 0);
    }
    const unsigned long long bal = __ballot(ok);
    if ((tid & 63) == 0) smi[tid >> 6] = (bal == ~0ULL) ? 1 : 0;
    __syncthreads();
    if (tid == 0) maskOK[(b * 8 + qt) * 16 + kt] = smi[0] & smi[1] & smi[2] & smi[3];
    return;
  }

  if (bid < 1345) {
    const int c0 = bid - 577;          // 0..767
#pragma unroll
    for (int it = 0; it < 8; ++it) {
      const size_t g = (size_t)(c0 + it * 768) * 2048 + (size_t)tid * 8;
      const int t = (int)(g >> 22);
      const float* base = (t == 0) ? Xq : (t == 1) ? Xk : Xv;
      const size_t off = g & 4194303;
      const float4 f0 = *(const float4*)(base + off);
      const float4 f1 = *(const float4*)(base + off + 4);
      *(bf16x8*)(Ab + g) = pack8(f0, f1);
    }
    return;
  }

  {
    const int c0 = bid - 1345;         // 0..191
#pragma unroll
    for (int it = 0; it < 8; ++it) {
      const size_t g = (size_t)(c0 + it * 192) * 2048 + (size_t)tid * 8;
      const int t = (int)(g >> 20);
      const float* W = (t == 0) ? Wq : (t == 1) ? Wk : Wv;
      const size_t off = g & 1048575;
      const float4 f0 = *(const float4*)(W + off);
      const float4 f1 = *(const float4*)(W + off + 4);
      *(bf16x8*)(Wb + g) = pack8(f0, f1);
    }
  }
}

// ---------------------------------------------------------------------------
// bf16 MFMA GEMM — ROUND-8 KERNEL RESTORED (best measured: 43.0 us, total
// 214.5). Round-9's T4 counted-vmcnt triple-buffer REGRESSED to 48.8 us with
// WRITE_SIZE amplification 24.5->47 MB (L2 pressure from deeper in-flight
// prefetch evicting partially-dirty lines) — confirming the catalog's regime
// gate: counted-vmcnt pays only inside an 8-phase role-split schedule, not a
// 2-phase loop (m218/m230/m233). Structure here: BK=32, As[2]/Ws[2] 4 KB
// each (32 KB total -> 3 blocks/CU), per iter {issue next tile's 4 async16
// FIRST -> 8 ds_read + 8 MFMA from live buffer -> ONE __syncthreads (its
// implicit vmcnt(0) drains the stage that overlapped with compute)}.
// LDS layout [row][slot], slot=(chunk+(row>>1))&3. C stored HEAD-MAJOR
// [head][4096][64], head = blockIdx.y*2 + wn.
// ---------------------------------------------------------------------------
__global__ __launch_bounds__(256) void gemm_qkv_bf16(
    const ushort* __restrict__ Ab, const ushort* __restrict__ Wb,
    const float* __restrict__ bq, const float* __restrict__ bk, const float* __restrict__ bv,
    ushort* __restrict__ QKVb) {
  const int z = blockIdx.z;
  const char* A = (const char*)(Ab + (size_t)z * 4194304);
  const char* W = (const char*)(Wb + (size_t)z * 1048576);
  const float* bias = (z == 0) ? bq : (z == 1) ? bk : bv;
  ushort* Cz = QKVb + (size_t)z * 4194304;
  const float scale = (z == 0) ? 0.125f : 1.0f;

  __shared__ ushort As[2][4096];  // 128 rows x 32 elts, slot-swizzled, 8 KB/buf
  __shared__ ushort Ws[2][4096];

  const int tid = threadIdx.x;
  const int lane = tid & 63, w = tid >> 6;
  const int l31 = lane & 31, kh = lane >> 5;   // 32x32 frag coords
  const int wn = w & 1, wm = w >> 1;
  const int m0 = blockIdx.x * 128, n0 = blockIdx.y * 128;

  // staging geometry: 512 chunks of 16 B; thread t covers L=t and L=256+t.
  // L -> row = L>>2, slot = L&3. Stored slot s holds global chunk
  // c = (s - ((row>>1)&3)) & 3 (inverse of the reader swizzle).
  const int rowA = tid >> 2;                       // rows 0..63
  const int cA = ((tid & 3) - ((rowA >> 1) & 3)) & 3;
  const int rowB = 64 + (tid >> 2);                // rows 64..127
  const int cB = ((tid & 3) - ((rowB >> 1) & 3)) & 3;

  f32x16 acc[2][2];
#pragma unroll
  for (int mt = 0; mt < 2; ++mt)
#pragma unroll
    for (int nt = 0; nt < 2; ++nt)
#pragma unroll
      for (int r = 0; r < 16; ++r) acc[mt][nt][r] = 0.f;

  // prologue: stage tile 0 into buffer 0, drain, publish
  async16(A + ((size_t)(m0 + rowA) * DD + cA * 8) * 2, &As[0][tid * 8]);
  async16(W + ((size_t)(n0 + rowA) * DD + cA * 8) * 2, &Ws[0][tid * 8]);
  async16(A + ((size_t)(m0 + rowB) * DD + cB * 8) * 2, &As[0][2048 + tid * 8]);
  async16(W + ((size_t)(n0 + rowB) * DD + cB * 8) * 2, &Ws[0][2048 + tid * 8]);
  __syncthreads();  // vmcnt(0) + barrier: tile 0 visible

  for (int i = 0; i < 32; ++i) {
    const int cur = i & 1;
    // issue next tile's stage FIRST -> overlaps with this tile's compute
    if (i < 31) {
      const int k0n = (i + 1) * 32;
      async16(A + ((size_t)(m0 + rowA) * DD + k0n + cA * 8) * 2, &As[cur ^ 1][tid * 8]);
      async16(W + ((size_t)(n0 + rowA) * DD + k0n + cA * 8) * 2, &Ws[cur ^ 1][tid * 8]);
      async16(A + ((size_t)(m0 + rowB) * DD + k0n + cB * 8) * 2, &As[cur ^ 1][2048 + tid * 8]);
      async16(W + ((size_t)(n0 + rowB) * DD + k0n + cB * 8) * 2, &Ws[cur ^ 1][2048 + tid * 8]);
    }
    // compute from the live buffer (2 K=16 steps)
#pragma unroll
    for (int ks = 0; ks < 2; ++ks) {
      bf16x8 wf[2], af[2];
#pragma unroll
      for (int nt = 0; nt < 2; ++nt) {
        const int r = wn * 64 + nt * 32 + l31;
        const int s = (ks * 2 + kh + ((r >> 1) & 3)) & 3;
        wf[nt] = *(const bf16x8*)&Ws[cur][r * 32 + s * 8];
      }
#pragma unroll
      for (int mt = 0; mt < 2; ++mt) {
        const int r = wm * 64 + mt * 32 + l31;
        const int s = (ks * 2 + kh + ((r >> 1) & 3)) & 3;
        af[mt] = *(const bf16x8*)&As[cur][r * 32 + s * 8];
      }
#pragma unroll
      for (int mt = 0; mt < 2; ++mt)
#pragma unroll
        for (int nt = 0; nt < 2; ++nt)
          acc[mt][nt] = __builtin_amdgcn_mfma_f32_32x32x16_bf16(wf[nt], af[mt], acc[mt][nt], 0, 0, 0);
    }
    // one barrier per K-step: drains my stage (vmcnt0) + closes read window
    __syncthreads();
  }

  // epilogue: bias + scale; head-major store [head][row][64]
  const int hh = blockIdx.y * 2 + wn;     // head owning this 64-col slab
#pragma unroll
  for (int nt = 0; nt < 2; ++nt) {
#pragma unroll
    for (int g = 0; g < 4; ++g) {
      const int ng = n0 + wn * 64 + nt * 32 + kh * 4 + g * 8;
      const int d = nt * 32 + kh * 4 + g * 8;          // dim within head
      const float4 b4 = *(const float4*)(bias + ng);
#pragma unroll
      for (int mt = 0; mt < 2; ++mt) {
        const int row = m0 + wm * 64 + mt * 32 + l31;
        ushort4 pk;
        pk.x = f2bf((acc[mt][nt][g * 4 + 0] + b4.x) * scale);
        pk.y = f2bf((acc[mt][nt][g * 4 + 1] + b4.y) * scale);
        pk.z = f2bf((acc[mt][nt][g * 4 + 2] + b4.z) * scale);
        pk.w = f2bf((acc[mt][nt][g * 4 + 3] + b4.w) * scale);
        *(ushort4*)&Cz[(size_t)hh * 262144 + (size_t)row * 64 + d] = pk;
      }
    }
  }
}

// ---------------------------------------------------------------------------
// MFMA flash attention — round-6 kernel, unchanged (dropped below the 41 us
// workspace-fill dispatch). Head-major QKV; K staged once per block via
// async16 into a double-buffered, granule-XOR-swizzled LDS tile; V-reg
// prefetch; two-barrier V publication; setprio MFMA clusters; okbits hoist.
// Grid (16,8,4), 2 blocks/CU.
// ---------------------------------------------------------------------------
__global__ __launch_bounds__(256) void flash_mfma(
    const ushort* __restrict__ QKVb, const int* __restrict__ mask,
    const int* __restrict__ maskOK, float* __restrict__ X) {
  __shared__ ushort Ks[2][4096];   // K tile 64 keys x 64 d, granule-swizzled
  __shared__ ushort Vt[64 * 72];   // V^T [d][key], padded
  __shared__ ushort Ps[128 * 72];  // P^T [q_local][key], padded

  const int tid = threadIdx.x;
  const int lane = tid & 63, w = tid >> 6;
  const int quad = lane >> 4, l15 = lane & 15;
  const int h = blockIdx.x, qblk = blockIdx.y, b = blockIdx.z;
  const int qbase = qblk * 128 + w * 32;

  // head-major bases: [h][4096][64]
  const ushort* Qh = QKVb + (size_t)h * 262144;
  const ushort* Kh = QKVb + 4194304 + (size_t)h * 262144 + (size_t)(b * SS) * 64;
  const ushort* Vh = QKVb + 8388608 + (size_t)h * 262144 + (size_t)(b * SS) * 64;

  bf16x8 qf[2][2];
#pragma unroll
  for (int qt = 0; qt < 2; ++qt)
#pragma unroll
    for (int ks = 0; ks < 2; ++ks)
      qf[qt][ks] = *(const bf16x8*)(Qh + (size_t)(b * SS + qbase + qt * 16 + l15) * 64 +
                                    ks * 32 + quad * 8);

  // per-tile mask flags -> bitmask
  unsigned okbits = 0;
  {
    const int* mkp = maskOK + (b * 8 + qblk) * 16;
#pragma unroll
    for (int i = 0; i < 16; ++i) okbits |= (mkp[i] ? 1u : 0u) << i;
  }

  f32x4 o[4][2];
  const f32x4 z4 = {0.f, 0.f, 0.f, 0.f};
#pragma unroll
  for (int dt = 0; dt < 4; ++dt)
#pragma unroll
    for (int qt = 0; qt < 2; ++qt) o[dt][qt] = z4;
  float l_run[2] = {0.f, 0.f};

  const int vp = tid & 31;   // key pair index
  const int vdc = tid >> 5;  // d-chunk (8 dims)
  const ushort* Vg = Vh + vdc * 8;
  uint* VtU = (uint*)Vt;
  const int* Mb = mask + (size_t)b * SS * SS;

  // K staging geometry: thread covers LDS chunks {tid, 256+tid} (16B each).
  const int r8k = tid >> 3;              // row within 32-row half
  const int gk = (tid & 7) ^ (r8k & 7);  // pre-swizzled source granule
  const int xk = l15 & 7;                // reader swizzle key (row&7)

  union U8 { uint4 u; ushort s[8]; };

  // ---- prologue: async K(0) -> Ks[0]; V(0) pair into regs ----
  async16(Kh + (size_t)r8k * 64 + gk * 8, &Ks[0][(size_t)tid * 8]);
  async16(Kh + (size_t)(32 + r8k) * 64 + gk * 8, &Ks[0][2048 + (size_t)tid * 8]);
  U8 v0c, v1c;
  v0c.u = *(const uint4*)(Vg + (size_t)(2 * vp) * 64);
  v1c.u = *(const uint4*)(Vg + (size_t)(2 * vp + 1) * 64);

  for (int kt = 0; kt < 16; ++kt) {
    const int k064 = kt * 64;
    const int cur = kt & 1;

    __builtin_amdgcn_s_barrier();   // B1: all waves done reading prior Vt/Ks
    // V transpose-write from prefetched regs; the implicit vmcnt wait for
    // v0c/v1c also drains this thread's older K asyncs (FIFO) -> Ks[cur]
    // complete in every thread before B2.
#pragma unroll
    for (int j = 0; j < 8; ++j)
      VtU[(vdc * 8 + j) * 36 + vp] = (uint)v0c.s[j] | ((uint)v1c.s[j] << 16);
    // stage K(kt+1) into the spare buffer (drains before B2 of iter kt+1)
    if (kt < 15) {
      const ushort* Kt = Kh + (size_t)(k064 + 64) * 64;
      async16(Kt + (size_t)r8k * 64 + gk * 8, &Ks[cur ^ 1][(size_t)tid * 8]);
      async16(Kt + (size_t)(32 + r8k) * 64 + gk * 8, &Ks[cur ^ 1][2048 + (size_t)tid * 8]);
    }
    asm volatile("s_waitcnt lgkmcnt(0)" ::: "memory");
    __builtin_amdgcn_sched_barrier(0);
    __builtin_amdgcn_s_barrier();   // B2: Vt + Ks[cur] visible to all waves

    // ---- V prefetch for tile kt+1 (consumed next iteration) ----
    const int kn = (kt < 15) ? (k064 + 64) : 0;  // clamp: dummy reload
    U8 v0n, v1n;
    v0n.u = *(const uint4*)(Vg + (size_t)(kn + 2 * vp) * 64);
    v1n.u = *(const uint4*)(Vg + (size_t)(kn + 2 * vp + 1) * 64);

    // ---- QK^T: K frags from swizzled LDS tile ----
    f32x4 s[4][2];
    __builtin_amdgcn_s_setprio(1);
#pragma unroll
    for (int mt = 0; mt < 4; ++mt) {
      const int rr = mt * 16 + l15;
      bf16x8 kf0 = *(const bf16x8*)&Ks[cur][rr * 64 + ((quad) ^ xk) * 8];
      bf16x8 kf1 = *(const bf16x8*)&Ks[cur][rr * 64 + ((4 + quad) ^ xk) * 8];
#pragma unroll
      for (int qt = 0; qt < 2; ++qt) {
        f32x4 a = z4;
        a = __builtin_amdgcn_mfma_f32_16x16x32_bf16(kf0, qf[qt][0], a, 0, 0, 0);
        a = __builtin_amdgcn_mfma_f32_16x16x32_bf16(kf1, qf[qt][1], a, 0, 0, 0);
        s[mt][qt] = a;
      }
    }
    __builtin_amdgcn_s_setprio(0);

    if (!((okbits >> kt) & 1)) {
#pragma unroll
      for (int mt = 0; mt < 4; ++mt)
#pragma unroll
        for (int qt = 0; qt < 2; ++qt)
#pragma unroll
          for (int reg = 0; reg < 4; ++reg) {
            const int q = qbase + qt * 16 + l15;
            const int key = k064 + mt * 16 + quad * 4 + reg;
            if (Mb[(size_t)q * SS + key] == 0) s[mt][qt][reg] = -1e9f;
          }
    }

#pragma unroll
    for (int qt = 0; qt < 2; ++qt) {
      float rs = 0.f;
#pragma unroll
      for (int mt = 0; mt < 4; ++mt) {
#pragma unroll
        for (int reg = 0; reg < 4; ++reg) {
          const float p = __expf(s[mt][qt][reg]);
          s[mt][qt][reg] = p;
          rs += p;
        }
      }
      l_run[qt] += rs;
#pragma unroll
      for (int mt = 0; mt < 4; ++mt) {
        ushort4 pk;
        pk.x = f2bf(s[mt][qt][0]);
        pk.y = f2bf(s[mt][qt][1]);
        pk.z = f2bf(s[mt][qt][2]);
        pk.w = f2bf(s[mt][qt][3]);
        *(ushort4*)&Ps[(w * 32 + qt * 16 + l15) * 72 + mt * 16 + quad * 4] = pk;
      }
    }

    // ---- PV (Ps same-wave; Vt barrier-protected) ----
    bf16x8 pf[2][2];
#pragma unroll
    for (int qt = 0; qt < 2; ++qt)
#pragma unroll
      for (int ks = 0; ks < 2; ++ks)
        pf[qt][ks] = *(const bf16x8*)&Ps[(w * 32 + qt * 16 + l15) * 72 + ks * 32 + quad * 8];
    __builtin_amdgcn_s_setprio(1);
#pragma unroll
    for (int dt = 0; dt < 4; ++dt) {
      bf16x8 vf0 = *(const bf16x8*)&Vt[(dt * 16 + l15) * 72 + quad * 8];
      bf16x8 vf1 = *(const bf16x8*)&Vt[(dt * 16 + l15) * 72 + 32 + quad * 8];
#pragma unroll
      for (int qt = 0; qt < 2; ++qt) {
        o[dt][qt] = __builtin_amdgcn_mfma_f32_16x16x32_bf16(vf0, pf[qt][0], o[dt][qt], 0, 0, 0);
        o[dt][qt] = __builtin_amdgcn_mfma_f32_16x16x32_bf16(vf1, pf[qt][1], o[dt][qt], 0, 0, 0);
      }
    }
    __builtin_amdgcn_s_setprio(0);

    // rotate prefetched V regs
    v0c.u = v0n.u;
    v1c.u = v1n.u;
  }

#pragma unroll
  for (int qt = 0; qt < 2; ++qt) {
    float l = l_run[qt];
    l += __shfl_xor(l, 16);
    l += __shfl_xor(l, 32);
    const float inv = 1.0f / l;
#pragma unroll
    for (int dt = 0; dt < 4; ++dt) {
      const f32x4 ov = o[dt][qt] * inv;
      *(f32x4*)(X + (size_t)(b * SS + qbase + qt * 16 + l15) * DD +
                h * DKH + dt * 16 + quad * 4) = ov;
    }
  }
}

// ---------------------------------------------------------------------------
// Epilogue: 4 rows per block (grid 1024), single barrier, wo slice in regs.
// xt = threshold(x,0.2); x1 = dot(xt,wo_sum)/1024 + bo_mean; out = xt + x1
// ---------------------------------------------------------------------------
__global__ __launch_bounds__(256) void epilogue_kernel(float* __restrict__ X,
                                                       const float* __restrict__ wo_sum,
                                                       const float* __restrict__ bo_mean) {
  __shared__ float red[4][4];
  const int tid = threadIdx.x;
  const float4 wv = *(const float4*)(wo_sum + tid * 4);
  const float bm = *bo_mean;
  float4 xt[4];
#pragma unroll
  for (int r = 0; r < 4; ++r) {
    const int row = blockIdx.x * 4 + r;
    const float4 x = *(const float4*)(X + (size_t)row * DD + tid * 4);
    xt[r].x = (x.x > 0.2f) ? x.x : 0.f;
    xt[r].y = (x.y > 0.2f) ? x.y : 0.f;
    xt[r].z = (x.z > 0.2f) ? x.z : 0.f;
    xt[r].w = (x.w > 0.2f) ? x.w : 0.f;
    float part = xt[r].x * wv.x + xt[r].y * wv.y + xt[r].z * wv.z + xt[r].w * wv.w;
#pragma unroll
    for (int off = 1; off < 64; off <<= 1) part += __shfl_xor(part, off);
    if ((tid & 63) == 0) red[r][tid >> 6] = part;
  }
  __syncthreads();
#pragma unroll
  for (int r = 0; r < 4; ++r) {
    const int row = blockIdx.x * 4 + r;
    const float x1 = ((red[r][0] + red[r][1]) + (red[r][2] + red[r][3])) * (1.0f / 1024.0f) + bm;
    const float4 o = make_float4(xt[r].x + x1, xt[r].y + x1, xt[r].z + x1, xt[r].w + x1);
    *(float4*)(X + (size_t)row * DD + tid * 4) = o;
  }
}

// ---------------------------------------------------------------------------
extern "C" void kernel_launch(void* const* d_in, const int* in_sizes, int n_in,
                              void* d_out, int out_size, void* d_ws, size_t ws_size,
                              hipStream_t stream) {
  const float* Xq = (const float*)d_in[0];
  const float* Xk = (const float*)d_in[1];
  const float* Xv = (const float*)d_in[2];
  const int* mask = (const int*)d_in[3];
  const float* Wq = (const float*)d_in[4];
  const float* bq = (const float*)d_in[5];
  const float* Wk = (const float*)d_in[6];
  const float* bk = (const float*)d_in[7];
  const float* Wv = (const float*)d_in[8];
  const float* bv = (const float*)d_in[9];
  const float* Wo = (const float*)d_in[10];
  const float* bo = (const float*)d_in[11];

  // workspace (~54 MB): Wb 6 MB + Ab 24 MB + QKVb 24 MB + tails
  ushort* Wb = (ushort*)d_ws;                     // 3 x 1048576 bf16
  ushort* Ab = Wb + (size_t)3 * 1048576;          // 3 x 4194304 bf16 (dense q,k,v)
  ushort* QKVb = Ab + (size_t)3 * 4194304;        // 3 x 4194304 bf16 (head-major)
  float* wo_sum = (float*)(QKVb + (size_t)3 * 4194304);
  float* bo_mean = wo_sum + 1024;
  int* maskOK = (int*)(bo_mean + 1);              // 512 ints
  float* X = (float*)d_out;

  hipMemsetAsync(wo_sum, 0, 1024 * sizeof(float), stream);

  prep_all<<<1537, 256, 0, stream>>>(Xq, Xk, Xv, mask, Wq, Wk, Wv, Wo, bo,
                                     Wb, Ab, wo_sum, bo_mean, maskOK);

  gemm_qkv_bf16<<<dim3(32, 8, 3), 256, 0, stream>>>(Ab, Wb, bq, bk, bv, QKVb);

  flash_mfma<<<dim3(16, 8, 4), 256, 0, stream>>>(QKVb, mask, maskOK, X);

  epilogue_kernel<<<1024, 256, 0, stream>>>(X, wo_sum, bo_mean);
}